// Round 17
// baseline (256.511 us; speedup 1.0000x reference)
//
#include <hip/hip_runtime.h>

#define HIDDEN 128
#define SCAN_B 1024

typedef float v2f __attribute__((ext_vector_type(2)));
typedef short short8 __attribute__((ext_vector_type(8)));
typedef float f32x4 __attribute__((ext_vector_type(4)));
__device__ __forceinline__ v2f v2s(float a) { v2f r; r.x = a; r.y = a; return r; }

// bf16 split helpers (RNE)
__device__ __forceinline__ ushort f2bf(float f) {
    uint u = __float_as_uint(f);
    u += 0x7FFFu + ((u >> 16) & 1u);
    return (ushort)(u >> 16);
}
__device__ __forceinline__ float bf2f(ushort h) {
    return __uint_as_float(((uint)h) << 16);
}

// opaque SGPR->VGPR move: defeats uniformity analysis so the following
// yv[idx] load MUST take the vector path (vmcnt-counted, pipelinable)
#define VMOV(dstv, srcs) asm volatile("v_mov_b32 %0, %1" : "=v"(dstv) : "s"(srcs))

// ================= CSR build (per call; no fp atomics anywhere) =============
__global__ __launch_bounds__(256)
void k_hist(const int* __restrict__ dst, int* __restrict__ cnt,
            int* __restrict__ rank, int E) {
    int e = blockIdx.x * 256 + threadIdx.x;
    if (e < E) rank[e] = atomicAdd(&cnt[dst[e]], 1);
}

__global__ __launch_bounds__(SCAN_B)
void k_scan1(const int* __restrict__ cnt, int* __restrict__ offs,
             int* __restrict__ bsum, int N) {
    __shared__ int sm[SCAN_B];
    int g = blockIdx.x * SCAN_B + threadIdx.x;
    int v = (g < N) ? cnt[g] : 0;
    int acc = v;
    sm[threadIdx.x] = v;
    __syncthreads();
    for (int d = 1; d < SCAN_B; d <<= 1) {
        int t = (threadIdx.x >= d) ? sm[threadIdx.x - d] : 0;
        __syncthreads();
        acc += t;
        sm[threadIdx.x] = acc;
        __syncthreads();
    }
    if (g < N) offs[g] = acc - v;                 // exclusive
    if (threadIdx.x == SCAN_B - 1) bsum[blockIdx.x] = acc;
}

__global__ __launch_bounds__(SCAN_B)
void k_scan2(int* __restrict__ bsum, int nb) {
    __shared__ int sm[SCAN_B];
    int v = (threadIdx.x < nb) ? bsum[threadIdx.x] : 0;
    int acc = v;
    sm[threadIdx.x] = v;
    __syncthreads();
    for (int d = 1; d < SCAN_B; d <<= 1) {
        int t = (threadIdx.x >= d) ? sm[threadIdx.x - d] : 0;
        __syncthreads();
        acc += t;
        sm[threadIdx.x] = acc;
        __syncthreads();
    }
    if (threadIdx.x < nb) bsum[threadIdx.x] = acc - v;   // exclusive
}

__global__ __launch_bounds__(SCAN_B)
void k_scan3(int* __restrict__ offs, const int* __restrict__ bsum, int N) {
    int g = blockIdx.x * SCAN_B + threadIdx.x;
    if (g < N) offs[g] += bsum[blockIdx.x];
}

// Scatter edges into CSR order. One 8B packed store per edge (src, w).
__global__ __launch_bounds__(256)
void k_fill(const int* __restrict__ src, const int* __restrict__ dst,
            const float* __restrict__ ew, const int* __restrict__ offs,
            const int* __restrict__ rank, int2* __restrict__ cpack, int E) {
    int e = blockIdx.x * 256 + threadIdx.x;
    if (e >= E) return;
    int d = dst[e];
    int slot = offs[d] + rank[e];
    int2 p;
    p.x = src[e];
    p.y = __float_as_int(ew[e]);
    cpack[slot] = p;
}

__device__ __forceinline__ int end_of(const int* offs, int i, int N, int E) {
    return (i + 1 < N) ? offs[i + 1] : E;
}

// ================= layer 1: gather 2ch, emit combined y = (a0,a1,x0,x1) ====
__global__ __launch_bounds__(256)
void k_gather2(const int* __restrict__ offs, const int2* __restrict__ cpack,
               const float* __restrict__ x, float4* __restrict__ yv,
               int N, int E) {
    int i = blockIdx.x * 256 + threadIdx.x;
    if (i >= N) return;
    int start = offs[i], end = end_of(offs, i, N, E);
    float a0 = 0.f, a1 = 0.f;
    for (int j = start; j < end; ++j) {
        int2  p = cpack[j];
        int   s = p.x;
        float w = __int_as_float(p.y);
        float2 xv = *reinterpret_cast<const float2*>(x + (size_t)s * 2);
        a0 = fmaf(w, xv.x, a0);
        a1 = fmaf(w, xv.y, a1);
    }
    float2 xi = *reinterpret_cast<const float2*>(x + (size_t)i * 2);
    yv[i] = make_float4(a0, a1, xi.x, xi.y);
}

// ================= fused layer-2 aggregation + layer-1 node update ==========
// R17: two-pipe edge loop. cpack stays on the SCALAR pipe (sequential,
// SGPR-resident). yv[s] moves to the VECTOR pipe via an opaque v_mov on the
// index (compiler would otherwise re-scalarize the uniform address):
// vmcnt is counted/in-order, so y-loads pipeline and the NEXT group's
// s_loads (lgkmcnt) overlap the current group's in-flight y-loads —
// breaking R16's SMEM-drain stop-and-go (SMEM returns OOO => any SMEM use
// forces lgkmcnt(0), draining everything; vmcnt has no such hazard).
#define EDGE4(sK, wK)                                              \
    {                                                              \
        v2f t = B + v2s((sK).x) * WR0 + v2s((sK).y) * WR1          \
                  + v2s((sK).z) * WO0 + v2s((sK).w) * WO1;         \
        t = __builtin_elementwise_max(t, Z);                       \
        acc = acc + v2s(wK) * t;                                   \
    }

__global__ __launch_bounds__(256)
void k_gatherfused(const int* __restrict__ offs, const int2* __restrict__ cpack,
                   const float4* __restrict__ yv,
                   const float* __restrict__ W1rel, const float* __restrict__ b1,
                   const float* __restrict__ W1root,
                   ushort* __restrict__ h_hi, ushort* __restrict__ h_lo,
                   ushort* __restrict__ a_hi, ushort* __restrict__ a_lo,
                   int N, int E) {
    int wv   = (blockIdx.x * 256 + threadIdx.x) >> 6;
    int lane = threadIdx.x & 63;
    if (wv >= N) return;
    wv = __builtin_amdgcn_readfirstlane(wv);   // force scalar: loop control uniform

    const int c0 = lane * 2;
    const v2f WR0 = *reinterpret_cast<const v2f*>(W1rel  + c0);
    const v2f WR1 = *reinterpret_cast<const v2f*>(W1rel  + HIDDEN + c0);
    const v2f WO0 = *reinterpret_cast<const v2f*>(W1root + c0);
    const v2f WO1 = *reinterpret_cast<const v2f*>(W1root + HIDDEN + c0);
    const v2f B   = *reinterpret_cast<const v2f*>(b1 + c0);
    const v2f Z   = {0.f, 0.f};

    int start = offs[wv];
    int end   = (wv + 1 < N) ? offs[wv + 1] : E;
    v2f acc = {0.f, 0.f};

    int j = start;
    for (; j + 8 <= end; j += 8) {
        // scalar pipe: 8 sequential 8B loads (SGPR)
        int2 p0 = cpack[j + 0]; int2 p1 = cpack[j + 1];
        int2 p2 = cpack[j + 2]; int2 p3 = cpack[j + 3];
        int2 p4 = cpack[j + 4]; int2 p5 = cpack[j + 5];
        int2 p6 = cpack[j + 6]; int2 p7 = cpack[j + 7];
        int s0 = __builtin_amdgcn_readfirstlane(p0.x);
        int s1 = __builtin_amdgcn_readfirstlane(p1.x);
        int s2 = __builtin_amdgcn_readfirstlane(p2.x);
        int s3 = __builtin_amdgcn_readfirstlane(p3.x);
        int s4 = __builtin_amdgcn_readfirstlane(p4.x);
        int s5 = __builtin_amdgcn_readfirstlane(p5.x);
        int s6 = __builtin_amdgcn_readfirstlane(p6.x);
        int s7 = __builtin_amdgcn_readfirstlane(p7.x);
        // vector pipe: opaque index -> global_load_dwordx4 (HW broadcast)
        int v0, v1, v2, v3, v4, v5, v6, v7;
        VMOV(v0, s0); VMOV(v1, s1); VMOV(v2, s2); VMOV(v3, s3);
        VMOV(v4, s4); VMOV(v5, s5); VMOV(v6, s6); VMOV(v7, s7);
        float4 y0 = yv[v0]; float4 y1 = yv[v1];
        float4 y2 = yv[v2]; float4 y3 = yv[v3];
        float4 y4 = yv[v4]; float4 y5 = yv[v5];
        float4 y6 = yv[v6]; float4 y7 = yv[v7];
        float w0 = __int_as_float(p0.y); float w1 = __int_as_float(p1.y);
        float w2 = __int_as_float(p2.y); float w3 = __int_as_float(p3.y);
        float w4 = __int_as_float(p4.y); float w5 = __int_as_float(p5.y);
        float w6 = __int_as_float(p6.y); float w7 = __int_as_float(p7.y);
        EDGE4(y0, w0) EDGE4(y1, w1) EDGE4(y2, w2) EDGE4(y3, w3)
        EDGE4(y4, w4) EDGE4(y5, w5) EDGE4(y6, w6) EDGE4(y7, w7)
    }
    for (; j + 4 <= end; j += 4) {
        int2 p0 = cpack[j + 0]; int2 p1 = cpack[j + 1];
        int2 p2 = cpack[j + 2]; int2 p3 = cpack[j + 3];
        int s0 = __builtin_amdgcn_readfirstlane(p0.x);
        int s1 = __builtin_amdgcn_readfirstlane(p1.x);
        int s2 = __builtin_amdgcn_readfirstlane(p2.x);
        int s3 = __builtin_amdgcn_readfirstlane(p3.x);
        int v0, v1, v2, v3;
        VMOV(v0, s0); VMOV(v1, s1); VMOV(v2, s2); VMOV(v3, s3);
        float4 y0 = yv[v0]; float4 y1 = yv[v1];
        float4 y2 = yv[v2]; float4 y3 = yv[v3];
        float w0 = __int_as_float(p0.y); float w1 = __int_as_float(p1.y);
        float w2 = __int_as_float(p2.y); float w3 = __int_as_float(p3.y);
        EDGE4(y0, w0) EDGE4(y1, w1) EDGE4(y2, w2) EDGE4(y3, w3)
    }
    for (; j < end; ++j) {                     // scalar tail (<=3)
        int2 p0 = cpack[j];
        int s0 = __builtin_amdgcn_readfirstlane(p0.x);
        int v0; VMOV(v0, s0);
        float4 y0 = yv[v0];
        float w0 = __int_as_float(p0.y);
        EDGE4(y0, w0)
    }

    // aggr -> bf16 hi/lo
    {
        ushort hx = f2bf(acc.x);
        ushort lx = f2bf(acc.x - bf2f(hx));
        ushort hy = f2bf(acc.y);
        ushort ly = f2bf(acc.y - bf2f(hy));
        ushort2 hv2; hv2.x = hx; hv2.y = hy;
        ushort2 lv2; lv2.x = lx; lv2.y = ly;
        *reinterpret_cast<ushort2*>(a_hi + (size_t)wv * HIDDEN + c0) = hv2;
        *reinterpret_cast<ushort2*>(a_lo + (size_t)wv * HIDDEN + c0) = lv2;
    }

    // fused k_node1: this wave's own h1 row -> bf16 hi/lo
    {
        float4 y = yv[wv];
        v2f t = B + v2s(y.x) * WR0 + v2s(y.y) * WR1
                  + v2s(y.z) * WO0 + v2s(y.w) * WO1;
        t = __builtin_elementwise_max(t, Z);
        ushort hx = f2bf(t.x);
        ushort lx = f2bf(t.x - bf2f(hx));
        ushort hy = f2bf(t.y);
        ushort ly = f2bf(t.y - bf2f(hy));
        ushort2 hv2; hv2.x = hx; hv2.y = hy;
        ushort2 lv2; lv2.x = lx; lv2.y = ly;
        *reinterpret_cast<ushort2*>(h_hi + (size_t)wv * HIDDEN + c0) = hv2;
        *reinterpret_cast<ushort2*>(h_lo + (size_t)wv * HIDDEN + c0) = lv2;
    }
}

// ================= one-shot W2 split + transpose ============================
__global__ __launch_bounds__(256)
void k_splitw(const float* __restrict__ Wrel, const float* __restrict__ Wroot,
              ushort* __restrict__ wThi, ushort* __restrict__ wTlo) {
    int idx = blockIdx.x * 256 + threadIdx.x;   // 0..32767
    int k = idx >> 7;          // 0..255
    int n = idx & 127;
    float v = (k < 128) ? Wrel[(size_t)k * HIDDEN + n]
                        : Wroot[(size_t)(k - 128) * HIDDEN + n];
    ushort hb = f2bf(v);
    ushort lb = f2bf(v - bf2f(hb));
    wThi[(size_t)n * 256 + k] = hb;
    wTlo[(size_t)n * 256 + k] = lb;
}

// ============ layer-2 node update on the MATRIX pipe + layer-3 fusion =======
#define BM2 64
#define W3_STRIDE 7
#define XS_LD 40   // ushorts per LDS row: 32 k + 8 pad (80B, 16B-aligned)

__global__ __launch_bounds__(256)
void k_node2(const ushort* __restrict__ a_hi, const ushort* __restrict__ a_lo,
             const ushort* __restrict__ h_hi, const ushort* __restrict__ h_lo,
             const ushort* __restrict__ wThi, const ushort* __restrict__ wTlo,
             const float* __restrict__ b,
             const float* __restrict__ W3rel, const float* __restrict__ b3,
             const float* __restrict__ W3root,
             float* __restrict__ z, float* __restrict__ out, int N) {
    __shared__ __align__(16) ushort Xhi[BM2 * XS_LD];
    __shared__ __align__(16) ushort Xlo[BM2 * XS_LD];
    __shared__ __align__(16) ushort Whi[HIDDEN * XS_LD];
    __shared__ __align__(16) ushort Wlo[HIDDEN * XS_LD];
    __shared__ float W3s[HIDDEN * W3_STRIDE];

    const int tid  = threadIdx.x;
    const int lane = tid & 63;
    const int wid  = tid >> 6;
    const int ci   = lane & 15;
    const int kb   = lane >> 4;          // k-block 0..3
    const int nb   = blockIdx.x * BM2;

    if (tid < HIDDEN) {
#pragma unroll
        for (int c = 0; c < 3; ++c) {
            W3s[tid * W3_STRIDE + c]     = W3rel [tid * 3 + c];
            W3s[tid * W3_STRIDE + 3 + c] = W3root[tid * 3 + c];
        }
    }

    f32x4 acc[8];
#pragma unroll
    for (int tile = 0; tile < 8; ++tile) {
        float bb = b[tile * 16 + ci];
        f32x4 v; v[0] = bb; v[1] = bb; v[2] = bb; v[3] = bb;
        acc[tile] = v;
    }

    // staging index precompute
    const int sr  = tid >> 2;            // X row 0..63
    const int skq = (tid & 3) * 8;       // X k offset {0,8,16,24}

    // K = 256: 8 phases of 32. t<4: aggr; t>=4: h. W index linear in t.
    for (int t = 0; t < 8; ++t) {
        const ushort* Ahi = (t < 4) ? a_hi : h_hi;
        const ushort* Alo = (t < 4) ? a_lo : h_lo;
        const int kc = (t & 3) * 32;

        __syncthreads();                 // previous compute done before overwrite
        // stage X tile (pre-split bf16): 1 b128 per array per thread
        {
            int gr = nb + sr; if (gr >= N) gr = N - 1;
            size_t gofs = (size_t)gr * HIDDEN + kc + skq;
            *reinterpret_cast<short8*>(&Xhi[sr * XS_LD + skq]) =
                *reinterpret_cast<const short8*>(Ahi + gofs);
            *reinterpret_cast<short8*>(&Xlo[sr * XS_LD + skq]) =
                *reinterpret_cast<const short8*>(Alo + gofs);
        }
        // stage W tile: pure b128 copy from pre-split pre-transposed wT
#pragma unroll
        for (int q = 0; q < 2; ++q) {
            int idx = q * 256 + tid;     // 0..511
            int n  = idx >> 2;           // 0..127
            int kq = (idx & 3) * 8;      // 0,8,16,24
            size_t g = (size_t)n * 256 + t * 32 + kq;
            *reinterpret_cast<short8*>(&Whi[n * XS_LD + kq]) =
                *reinterpret_cast<const short8*>(wThi + g);
            *reinterpret_cast<short8*>(&Wlo[n * XS_LD + kq]) =
                *reinterpret_cast<const short8*>(wTlo + g);
        }
        __syncthreads();

        // A frags for this wave's 16-row tile (shared across all col tiles)
        int rl = wid * 16 + ci;
        short8 afh = *reinterpret_cast<const short8*>(&Xhi[rl * XS_LD + kb * 8]);
        short8 afl = *reinterpret_cast<const short8*>(&Xlo[rl * XS_LD + kb * 8]);
#pragma unroll
        for (int tile = 0; tile < 8; ++tile) {
            int nl = tile * 16 + ci;
            short8 bfh = *reinterpret_cast<const short8*>(&Whi[nl * XS_LD + kb * 8]);
            short8 bfl = *reinterpret_cast<const short8*>(&Wlo[nl * XS_LD + kb * 8]);
            acc[tile] = __builtin_amdgcn_mfma_f32_16x16x32_bf16(afh, bfh, acc[tile], 0, 0, 0);
            acc[tile] = __builtin_amdgcn_mfma_f32_16x16x32_bf16(afh, bfl, acc[tile], 0, 0, 0);
            acc[tile] = __builtin_amdgcn_mfma_f32_16x16x32_bf16(afl, bfh, acc[tile], 0, 0, 0);
        }
    }

    // epilogue: relu -> per-thread rank-8 partials vs LDS W3 -> width-16 shfl
    // D layout: row = kb*4 + m within wave tile, ch = tile*16 + ci
    const float b30 = b3[0], b31 = b3[1], b32 = b3[2];
#pragma unroll
    for (int m = 0; m < 4; ++m) {
        int node = nb + wid * 16 + kb * 4 + m;
        float zr0 = 0.f, zr1 = 0.f, zr2 = 0.f;
        float zo0 = 0.f, zo1 = 0.f, zo2 = 0.f;
#pragma unroll
        for (int tile = 0; tile < 8; ++tile) {
            float hv = fmaxf(acc[tile][m], 0.f);
            const float* w3 = &W3s[(tile * 16 + ci) * W3_STRIDE];
            zr0 = fmaf(hv, w3[0], zr0); zr1 = fmaf(hv, w3[1], zr1); zr2 = fmaf(hv, w3[2], zr2);
            zo0 = fmaf(hv, w3[3], zo0); zo1 = fmaf(hv, w3[4], zo1); zo2 = fmaf(hv, w3[5], zo2);
        }
#pragma unroll
        for (int d = 8; d >= 1; d >>= 1) {
            zr0 += __shfl_down(zr0, d, 16);
            zr1 += __shfl_down(zr1, d, 16);
            zr2 += __shfl_down(zr2, d, 16);
            zo0 += __shfl_down(zo0, d, 16);
            zo1 += __shfl_down(zo1, d, 16);
            zo2 += __shfl_down(zo2, d, 16);
        }
        if (ci == 0 && node < N) {
            z[(size_t)node * 3 + 0] = zr0;
            z[(size_t)node * 3 + 1] = zr1;
            z[(size_t)node * 3 + 2] = zr2;
            out[(size_t)node * 3 + 0] = zo0 + b30;
            out[(size_t)node * 3 + 1] = zo1 + b31;
            out[(size_t)node * 3 + 2] = zo2 + b32;
        }
    }
}

// ================= layer 3 gather =====================
__global__ __launch_bounds__(256)
void k_gather3(const int* __restrict__ offs, const int2* __restrict__ cpack,
               const float* __restrict__ z, float* __restrict__ out,
               int N, int E) {
    int i = blockIdx.x * 256 + threadIdx.x;
    if (i >= N) return;
    int start = offs[i], end = end_of(offs, i, N, E);
    float a0 = 0.f, a1 = 0.f, a2 = 0.f;
    for (int j = start; j < end; ++j) {
        int2  p = cpack[j];
        int   s = p.x;
        float w = __int_as_float(p.y);
        const float* zp = z + (size_t)s * 3;
        a0 = fmaf(w, zp[0], a0);
        a1 = fmaf(w, zp[1], a1);
        a2 = fmaf(w, zp[2], a2);
    }
    out[(size_t)i * 3 + 0] += a0;
    out[(size_t)i * 3 + 1] += a1;
    out[(size_t)i * 3 + 2] += a2;
}

extern "C" void kernel_launch(void* const* d_in, const int* in_sizes, int n_in,
                              void* d_out, int out_size, void* d_ws, size_t ws_size,
                              hipStream_t stream) {
    const float* x      = (const float*)d_in[0];
    const int*   ei     = (const int*)  d_in[1];
    const float* ew     = (const float*)d_in[2];
    const float* W1rel  = (const float*)d_in[4];
    const float* b1     = (const float*)d_in[5];
    const float* W1root = (const float*)d_in[6];
    const float* W2rel  = (const float*)d_in[7];
    const float* b2     = (const float*)d_in[8];
    const float* W2root = (const float*)d_in[9];
    const float* W3rel  = (const float*)d_in[10];
    const float* b3     = (const float*)d_in[11];
    const float* W3root = (const float*)d_in[12];
    float* out = (float*)d_out;

    const int N = in_sizes[0] / 2;
    const int E = in_sizes[2];
    const int* src = ei;
    const int* dst = ei + E;

    // -------- workspace layout (same total size as R16) --------
    ushort* h_hi = (ushort*)d_ws;
    ushort* h_lo = h_hi + (size_t)N * HIDDEN;
    ushort* a_hi = h_lo + (size_t)N * HIDDEN;
    ushort* a_lo = a_hi + (size_t)N * HIDDEN;
    int*   offs = (int*)(a_lo + (size_t)N * HIDDEN);
    int*   bsum = offs + N;
    size_t cpo  = (size_t)(bsum + SCAN_B - (int*)d_ws);
    cpo = (cpo + 1) & ~(size_t)1;          // 8B alignment
    int2*   cpack = (int2*)((int*)d_ws + cpo);
    size_t yvo  = (size_t)((char*)(cpack + E) - (char*)d_ws);
    yvo = (yvo + 15) & ~(size_t)15;        // 16B alignment
    float4* yv  = (float4*)((char*)d_ws + yvo);
    int* cnt  = (int*)cpack;               // alias: dead before k_fill writes cpack
    int* rank = (int*)d_ws;                // alias: dead before gatherfused writes h_hi
    float* z  = (float*)yv;                // alias: yv dead after gatherfused
    size_t wto = yvo + ((size_t)N * 3 * sizeof(float) + 15 & ~(size_t)15);
    wto = (wto + 15) & ~(size_t)15;
    ushort* wThi = (ushort*)((char*)d_ws + wto);          // 64KB
    ushort* wTlo = wThi + 128 * 256;                       // 64KB (within yv tail)

    const int nbScan = (N + SCAN_B - 1) / SCAN_B;

    // -------- CSR build --------
    hipMemsetAsync(cnt, 0, (size_t)N * sizeof(int), stream);
    k_hist <<<(E + 255) / 256, 256, 0, stream>>>(dst, cnt, rank, E);
    k_scan1<<<nbScan, SCAN_B, 0, stream>>>(cnt, offs, bsum, N);
    k_scan2<<<1, SCAN_B, 0, stream>>>(bsum, nbScan);
    k_scan3<<<nbScan, SCAN_B, 0, stream>>>(offs, bsum, N);
    k_fill <<<(E + 255) / 256, 256, 0, stream>>>(src, dst, ew, offs, rank, cpack, E);

    // -------- layer 1 aggregation (2ch) + y pack --------
    k_gather2<<<(N + 255) / 256, 256, 0, stream>>>(offs, cpack, x, yv, N, E);

    // -------- fused layer-2 aggregation + layer-1 node update (bf16 out) ----
    {
        long long threads = (long long)N * 64;
        k_gatherfused<<<(int)((threads + 255) / 256), 256, 0, stream>>>(
            offs, cpack, yv, W1rel, b1, W1root, h_hi, h_lo, a_hi, a_lo, N, E);
    }

    // -------- one-shot W2 split+transpose (yv dead now; writes its tail) ----
    k_splitw<<<128, 256, 0, stream>>>(W2rel, W2root, wThi, wTlo);

    // -------- MFMA layer-2 node update + layer-3 projection --------
    k_node2<<<(N + BM2 - 1) / BM2, 256, 0, stream>>>(
        a_hi, a_lo, h_hi, h_lo, wThi, wTlo, b2, W3rel, b3, W3root, z, out, N);

    // -------- layer 3 gather --------
    k_gather3<<<(N + 255) / 256, 256, 0, stream>>>(offs, cpack, z, out, N, E);
}

// Round 18
// 249.450 us; speedup vs baseline: 1.0283x; 1.0283x over previous
//
#include <hip/hip_runtime.h>

#define HIDDEN 128
#define SCAN_B 1024

typedef float v2f __attribute__((ext_vector_type(2)));
typedef short short8 __attribute__((ext_vector_type(8)));
typedef float f32x4 __attribute__((ext_vector_type(4)));
__device__ __forceinline__ v2f v2s(float a) { v2f r; r.x = a; r.y = a; return r; }

// bf16 split helpers (RNE)
__device__ __forceinline__ ushort f2bf(float f) {
    uint u = __float_as_uint(f);
    u += 0x7FFFu + ((u >> 16) & 1u);
    return (ushort)(u >> 16);
}
__device__ __forceinline__ float bf2f(ushort h) {
    return __uint_as_float(((uint)h) << 16);
}

// ================= CSR build (per call; no fp atomics anywhere) =============
__global__ __launch_bounds__(256)
void k_hist(const int* __restrict__ dst, int* __restrict__ cnt,
            int* __restrict__ rank, int E) {
    int e = blockIdx.x * 256 + threadIdx.x;
    if (e < E) rank[e] = atomicAdd(&cnt[dst[e]], 1);
}

__global__ __launch_bounds__(SCAN_B)
void k_scan1(const int* __restrict__ cnt, int* __restrict__ offs,
             int* __restrict__ bsum, int N) {
    __shared__ int sm[SCAN_B];
    int g = blockIdx.x * SCAN_B + threadIdx.x;
    int v = (g < N) ? cnt[g] : 0;
    int acc = v;
    sm[threadIdx.x] = v;
    __syncthreads();
    for (int d = 1; d < SCAN_B; d <<= 1) {
        int t = (threadIdx.x >= d) ? sm[threadIdx.x - d] : 0;
        __syncthreads();
        acc += t;
        sm[threadIdx.x] = acc;
        __syncthreads();
    }
    if (g < N) offs[g] = acc - v;                 // exclusive
    if (threadIdx.x == SCAN_B - 1) bsum[blockIdx.x] = acc;
}

__global__ __launch_bounds__(SCAN_B)
void k_scan2(int* __restrict__ bsum, int nb) {
    __shared__ int sm[SCAN_B];
    int v = (threadIdx.x < nb) ? bsum[threadIdx.x] : 0;
    int acc = v;
    sm[threadIdx.x] = v;
    __syncthreads();
    for (int d = 1; d < SCAN_B; d <<= 1) {
        int t = (threadIdx.x >= d) ? sm[threadIdx.x - d] : 0;
        __syncthreads();
        acc += t;
        sm[threadIdx.x] = acc;
        __syncthreads();
    }
    if (threadIdx.x < nb) bsum[threadIdx.x] = acc - v;   // exclusive
}

__global__ __launch_bounds__(SCAN_B)
void k_scan3(int* __restrict__ offs, const int* __restrict__ bsum, int N) {
    int g = blockIdx.x * SCAN_B + threadIdx.x;
    if (g < N) offs[g] += bsum[blockIdx.x];
}

// Scatter edges into CSR order. One 8B packed store per edge (src, w).
__global__ __launch_bounds__(256)
void k_fill(const int* __restrict__ src, const int* __restrict__ dst,
            const float* __restrict__ ew, const int* __restrict__ offs,
            const int* __restrict__ rank, int2* __restrict__ cpack, int E) {
    int e = blockIdx.x * 256 + threadIdx.x;
    if (e >= E) return;
    int d = dst[e];
    int slot = offs[d] + rank[e];
    int2 p;
    p.x = src[e];
    p.y = __float_as_int(ew[e]);
    cpack[slot] = p;
}

__device__ __forceinline__ int end_of(const int* offs, int i, int N, int E) {
    return (i + 1 < N) ? offs[i + 1] : E;
}

// ================= layer 1: gather 2ch, emit combined y = (a0,a1,x0,x1) ====
__global__ __launch_bounds__(256)
void k_gather2(const int* __restrict__ offs, const int2* __restrict__ cpack,
               const float* __restrict__ x, float4* __restrict__ yv,
               int N, int E) {
    int i = blockIdx.x * 256 + threadIdx.x;
    if (i >= N) return;
    int start = offs[i], end = end_of(offs, i, N, E);
    float a0 = 0.f, a1 = 0.f;
    for (int j = start; j < end; ++j) {
        int2  p = cpack[j];
        int   s = p.x;
        float w = __int_as_float(p.y);
        float2 xv = *reinterpret_cast<const float2*>(x + (size_t)s * 2);
        a0 = fmaf(w, xv.x, a0);
        a1 = fmaf(w, xv.y, a1);
    }
    float2 xi = *reinterpret_cast<const float2*>(x + (size_t)i * 2);
    yv[i] = make_float4(a0, a1, xi.x, xi.y);
}

// ================= fused layer-2 aggregation + layer-1 node update ==========
// R18: one-SMEM-round-trip edge loop. Window staging is ONE coalesced
// vector load (cpack[base+lane], vmcnt-counted — independent of lgkmcnt);
// per-edge broadcast via v_readlane (VALU->SGPR, no DS pipe, provably
// uniform result) so yv[s] stays an s_load_dwordx4 (R16's scalarization).
// This removes R16's first SMEM level (cpack s_loads + their drain):
// SMEM returns are OOO so every use forces lgkmcnt(0) — halving the
// round-trips halves the serial stall. R17's vector-yv variant regressed
// (per-lane broadcast load overhead) and is reverted.
#define EDGE4(sK, wK)                                              \
    {                                                              \
        v2f t = B + v2s((sK).x) * WR0 + v2s((sK).y) * WR1          \
                  + v2s((sK).z) * WO0 + v2s((sK).w) * WO1;         \
        t = __builtin_elementwise_max(t, Z);                       \
        acc = acc + v2s(wK) * t;                                   \
    }

__global__ __launch_bounds__(256)
void k_gatherfused(const int* __restrict__ offs, const int2* __restrict__ cpack,
                   const float4* __restrict__ yv,
                   const float* __restrict__ W1rel, const float* __restrict__ b1,
                   const float* __restrict__ W1root,
                   ushort* __restrict__ h_hi, ushort* __restrict__ h_lo,
                   ushort* __restrict__ a_hi, ushort* __restrict__ a_lo,
                   int N, int E) {
    int wv   = (blockIdx.x * 256 + threadIdx.x) >> 6;
    int lane = threadIdx.x & 63;
    if (wv >= N) return;
    wv = __builtin_amdgcn_readfirstlane(wv);   // force scalar: loop control uniform

    const int c0 = lane * 2;
    const v2f WR0 = *reinterpret_cast<const v2f*>(W1rel  + c0);
    const v2f WR1 = *reinterpret_cast<const v2f*>(W1rel  + HIDDEN + c0);
    const v2f WO0 = *reinterpret_cast<const v2f*>(W1root + c0);
    const v2f WO1 = *reinterpret_cast<const v2f*>(W1root + HIDDEN + c0);
    const v2f B   = *reinterpret_cast<const v2f*>(b1 + c0);
    const v2f Z   = {0.f, 0.f};

    int start = offs[wv];
    int end   = (wv + 1 < N) ? offs[wv + 1] : E;
    v2f acc = {0.f, 0.f};

    for (int base = start; base < end; base += 64) {
        int nb = min(64, end - base);
        int sx = 0, wb = 0;
        if (lane < nb) {                       // ONE coalesced 8B/lane load
            int2 p = cpack[base + lane];
            sx = p.x; wb = p.y;
        }
        int k = 0;
        for (; k + 8 <= nb; k += 8) {
            // broadcast via readlane (VALU, uniform result) -> s_load yv
            int s0 = __builtin_amdgcn_readlane(sx, k + 0);
            int s1 = __builtin_amdgcn_readlane(sx, k + 1);
            int s2 = __builtin_amdgcn_readlane(sx, k + 2);
            int s3 = __builtin_amdgcn_readlane(sx, k + 3);
            int s4 = __builtin_amdgcn_readlane(sx, k + 4);
            int s5 = __builtin_amdgcn_readlane(sx, k + 5);
            int s6 = __builtin_amdgcn_readlane(sx, k + 6);
            int s7 = __builtin_amdgcn_readlane(sx, k + 7);
            float4 y0 = yv[s0]; float4 y1 = yv[s1];
            float4 y2 = yv[s2]; float4 y3 = yv[s3];
            float4 y4 = yv[s4]; float4 y5 = yv[s5];
            float4 y6 = yv[s6]; float4 y7 = yv[s7];
            float w0 = __int_as_float(__builtin_amdgcn_readlane(wb, k + 0));
            float w1 = __int_as_float(__builtin_amdgcn_readlane(wb, k + 1));
            float w2 = __int_as_float(__builtin_amdgcn_readlane(wb, k + 2));
            float w3 = __int_as_float(__builtin_amdgcn_readlane(wb, k + 3));
            float w4 = __int_as_float(__builtin_amdgcn_readlane(wb, k + 4));
            float w5 = __int_as_float(__builtin_amdgcn_readlane(wb, k + 5));
            float w6 = __int_as_float(__builtin_amdgcn_readlane(wb, k + 6));
            float w7 = __int_as_float(__builtin_amdgcn_readlane(wb, k + 7));
            EDGE4(y0, w0) EDGE4(y1, w1) EDGE4(y2, w2) EDGE4(y3, w3)
            EDGE4(y4, w4) EDGE4(y5, w5) EDGE4(y6, w6) EDGE4(y7, w7)
        }
        for (; k + 4 <= nb; k += 4) {
            int s0 = __builtin_amdgcn_readlane(sx, k + 0);
            int s1 = __builtin_amdgcn_readlane(sx, k + 1);
            int s2 = __builtin_amdgcn_readlane(sx, k + 2);
            int s3 = __builtin_amdgcn_readlane(sx, k + 3);
            float4 y0 = yv[s0]; float4 y1 = yv[s1];
            float4 y2 = yv[s2]; float4 y3 = yv[s3];
            float w0 = __int_as_float(__builtin_amdgcn_readlane(wb, k + 0));
            float w1 = __int_as_float(__builtin_amdgcn_readlane(wb, k + 1));
            float w2 = __int_as_float(__builtin_amdgcn_readlane(wb, k + 2));
            float w3 = __int_as_float(__builtin_amdgcn_readlane(wb, k + 3));
            EDGE4(y0, w0) EDGE4(y1, w1) EDGE4(y2, w2) EDGE4(y3, w3)
        }
        for (; k < nb; ++k) {                  // scalar tail (<=3)
            int s0 = __builtin_amdgcn_readlane(sx, k);
            float4 y0 = yv[s0];
            float w0 = __int_as_float(__builtin_amdgcn_readlane(wb, k));
            EDGE4(y0, w0)
        }
    }

    // aggr -> bf16 hi/lo
    {
        ushort hx = f2bf(acc.x);
        ushort lx = f2bf(acc.x - bf2f(hx));
        ushort hy = f2bf(acc.y);
        ushort ly = f2bf(acc.y - bf2f(hy));
        ushort2 hv2; hv2.x = hx; hv2.y = hy;
        ushort2 lv2; lv2.x = lx; lv2.y = ly;
        *reinterpret_cast<ushort2*>(a_hi + (size_t)wv * HIDDEN + c0) = hv2;
        *reinterpret_cast<ushort2*>(a_lo + (size_t)wv * HIDDEN + c0) = lv2;
    }

    // fused k_node1: this wave's own h1 row -> bf16 hi/lo
    {
        float4 y = yv[wv];
        v2f t = B + v2s(y.x) * WR0 + v2s(y.y) * WR1
                  + v2s(y.z) * WO0 + v2s(y.w) * WO1;
        t = __builtin_elementwise_max(t, Z);
        ushort hx = f2bf(t.x);
        ushort lx = f2bf(t.x - bf2f(hx));
        ushort hy = f2bf(t.y);
        ushort ly = f2bf(t.y - bf2f(hy));
        ushort2 hv2; hv2.x = hx; hv2.y = hy;
        ushort2 lv2; lv2.x = lx; lv2.y = ly;
        *reinterpret_cast<ushort2*>(h_hi + (size_t)wv * HIDDEN + c0) = hv2;
        *reinterpret_cast<ushort2*>(h_lo + (size_t)wv * HIDDEN + c0) = lv2;
    }
}

// ================= one-shot W2 split + transpose ============================
__global__ __launch_bounds__(256)
void k_splitw(const float* __restrict__ Wrel, const float* __restrict__ Wroot,
              ushort* __restrict__ wThi, ushort* __restrict__ wTlo) {
    int idx = blockIdx.x * 256 + threadIdx.x;   // 0..32767
    int k = idx >> 7;          // 0..255
    int n = idx & 127;
    float v = (k < 128) ? Wrel[(size_t)k * HIDDEN + n]
                        : Wroot[(size_t)(k - 128) * HIDDEN + n];
    ushort hb = f2bf(v);
    ushort lb = f2bf(v - bf2f(hb));
    wThi[(size_t)n * 256 + k] = hb;
    wTlo[(size_t)n * 256 + k] = lb;
}

// ============ layer-2 node update on the MATRIX pipe + layer-3 fusion =======
#define BM2 64
#define W3_STRIDE 7
#define XS_LD 40   // ushorts per LDS row: 32 k + 8 pad (80B, 16B-aligned)

__global__ __launch_bounds__(256)
void k_node2(const ushort* __restrict__ a_hi, const ushort* __restrict__ a_lo,
             const ushort* __restrict__ h_hi, const ushort* __restrict__ h_lo,
             const ushort* __restrict__ wThi, const ushort* __restrict__ wTlo,
             const float* __restrict__ b,
             const float* __restrict__ W3rel, const float* __restrict__ b3,
             const float* __restrict__ W3root,
             float* __restrict__ z, float* __restrict__ out, int N) {
    __shared__ __align__(16) ushort Xhi[BM2 * XS_LD];
    __shared__ __align__(16) ushort Xlo[BM2 * XS_LD];
    __shared__ __align__(16) ushort Whi[HIDDEN * XS_LD];
    __shared__ __align__(16) ushort Wlo[HIDDEN * XS_LD];
    __shared__ float W3s[HIDDEN * W3_STRIDE];

    const int tid  = threadIdx.x;
    const int lane = tid & 63;
    const int wid  = tid >> 6;
    const int ci   = lane & 15;
    const int kb   = lane >> 4;          // k-block 0..3
    const int nb   = blockIdx.x * BM2;

    if (tid < HIDDEN) {
#pragma unroll
        for (int c = 0; c < 3; ++c) {
            W3s[tid * W3_STRIDE + c]     = W3rel [tid * 3 + c];
            W3s[tid * W3_STRIDE + 3 + c] = W3root[tid * 3 + c];
        }
    }

    f32x4 acc[8];
#pragma unroll
    for (int tile = 0; tile < 8; ++tile) {
        float bb = b[tile * 16 + ci];
        f32x4 v; v[0] = bb; v[1] = bb; v[2] = bb; v[3] = bb;
        acc[tile] = v;
    }

    // staging index precompute
    const int sr  = tid >> 2;            // X row 0..63
    const int skq = (tid & 3) * 8;       // X k offset {0,8,16,24}

    // K = 256: 8 phases of 32. t<4: aggr; t>=4: h. W index linear in t.
    for (int t = 0; t < 8; ++t) {
        const ushort* Ahi = (t < 4) ? a_hi : h_hi;
        const ushort* Alo = (t < 4) ? a_lo : h_lo;
        const int kc = (t & 3) * 32;

        __syncthreads();                 // previous compute done before overwrite
        // stage X tile (pre-split bf16): 1 b128 per array per thread
        {
            int gr = nb + sr; if (gr >= N) gr = N - 1;
            size_t gofs = (size_t)gr * HIDDEN + kc + skq;
            *reinterpret_cast<short8*>(&Xhi[sr * XS_LD + skq]) =
                *reinterpret_cast<const short8*>(Ahi + gofs);
            *reinterpret_cast<short8*>(&Xlo[sr * XS_LD + skq]) =
                *reinterpret_cast<const short8*>(Alo + gofs);
        }
        // stage W tile: pure b128 copy from pre-split pre-transposed wT
#pragma unroll
        for (int q = 0; q < 2; ++q) {
            int idx = q * 256 + tid;     // 0..511
            int n  = idx >> 2;           // 0..127
            int kq = (idx & 3) * 8;      // 0,8,16,24
            size_t g = (size_t)n * 256 + t * 32 + kq;
            *reinterpret_cast<short8*>(&Whi[n * XS_LD + kq]) =
                *reinterpret_cast<const short8*>(wThi + g);
            *reinterpret_cast<short8*>(&Wlo[n * XS_LD + kq]) =
                *reinterpret_cast<const short8*>(wTlo + g);
        }
        __syncthreads();

        // A frags for this wave's 16-row tile (shared across all col tiles)
        int rl = wid * 16 + ci;
        short8 afh = *reinterpret_cast<const short8*>(&Xhi[rl * XS_LD + kb * 8]);
        short8 afl = *reinterpret_cast<const short8*>(&Xlo[rl * XS_LD + kb * 8]);
#pragma unroll
        for (int tile = 0; tile < 8; ++tile) {
            int nl = tile * 16 + ci;
            short8 bfh = *reinterpret_cast<const short8*>(&Whi[nl * XS_LD + kb * 8]);
            short8 bfl = *reinterpret_cast<const short8*>(&Wlo[nl * XS_LD + kb * 8]);
            acc[tile] = __builtin_amdgcn_mfma_f32_16x16x32_bf16(afh, bfh, acc[tile], 0, 0, 0);
            acc[tile] = __builtin_amdgcn_mfma_f32_16x16x32_bf16(afh, bfl, acc[tile], 0, 0, 0);
            acc[tile] = __builtin_amdgcn_mfma_f32_16x16x32_bf16(afl, bfh, acc[tile], 0, 0, 0);
        }
    }

    // epilogue: relu -> per-thread rank-8 partials vs LDS W3 -> width-16 shfl
    // D layout: row = kb*4 + m within wave tile, ch = tile*16 + ci
    const float b30 = b3[0], b31 = b3[1], b32 = b3[2];
#pragma unroll
    for (int m = 0; m < 4; ++m) {
        int node = nb + wid * 16 + kb * 4 + m;
        float zr0 = 0.f, zr1 = 0.f, zr2 = 0.f;
        float zo0 = 0.f, zo1 = 0.f, zo2 = 0.f;
#pragma unroll
        for (int tile = 0; tile < 8; ++tile) {
            float hv = fmaxf(acc[tile][m], 0.f);
            const float* w3 = &W3s[(tile * 16 + ci) * W3_STRIDE];
            zr0 = fmaf(hv, w3[0], zr0); zr1 = fmaf(hv, w3[1], zr1); zr2 = fmaf(hv, w3[2], zr2);
            zo0 = fmaf(hv, w3[3], zo0); zo1 = fmaf(hv, w3[4], zo1); zo2 = fmaf(hv, w3[5], zo2);
        }
#pragma unroll
        for (int d = 8; d >= 1; d >>= 1) {
            zr0 += __shfl_down(zr0, d, 16);
            zr1 += __shfl_down(zr1, d, 16);
            zr2 += __shfl_down(zr2, d, 16);
            zo0 += __shfl_down(zo0, d, 16);
            zo1 += __shfl_down(zo1, d, 16);
            zo2 += __shfl_down(zo2, d, 16);
        }
        if (ci == 0 && node < N) {
            z[(size_t)node * 3 + 0] = zr0;
            z[(size_t)node * 3 + 1] = zr1;
            z[(size_t)node * 3 + 2] = zr2;
            out[(size_t)node * 3 + 0] = zo0 + b30;
            out[(size_t)node * 3 + 1] = zo1 + b31;
            out[(size_t)node * 3 + 2] = zo2 + b32;
        }
    }
}

// ================= layer 3 gather =====================
__global__ __launch_bounds__(256)
void k_gather3(const int* __restrict__ offs, const int2* __restrict__ cpack,
               const float* __restrict__ z, float* __restrict__ out,
               int N, int E) {
    int i = blockIdx.x * 256 + threadIdx.x;
    if (i >= N) return;
    int start = offs[i], end = end_of(offs, i, N, E);
    float a0 = 0.f, a1 = 0.f, a2 = 0.f;
    for (int j = start; j < end; ++j) {
        int2  p = cpack[j];
        int   s = p.x;
        float w = __int_as_float(p.y);
        const float* zp = z + (size_t)s * 3;
        a0 = fmaf(w, zp[0], a0);
        a1 = fmaf(w, zp[1], a1);
        a2 = fmaf(w, zp[2], a2);
    }
    out[(size_t)i * 3 + 0] += a0;
    out[(size_t)i * 3 + 1] += a1;
    out[(size_t)i * 3 + 2] += a2;
}

extern "C" void kernel_launch(void* const* d_in, const int* in_sizes, int n_in,
                              void* d_out, int out_size, void* d_ws, size_t ws_size,
                              hipStream_t stream) {
    const float* x      = (const float*)d_in[0];
    const int*   ei     = (const int*)  d_in[1];
    const float* ew     = (const float*)d_in[2];
    const float* W1rel  = (const float*)d_in[4];
    const float* b1     = (const float*)d_in[5];
    const float* W1root = (const float*)d_in[6];
    const float* W2rel  = (const float*)d_in[7];
    const float* b2     = (const float*)d_in[8];
    const float* W2root = (const float*)d_in[9];
    const float* W3rel  = (const float*)d_in[10];
    const float* b3     = (const float*)d_in[11];
    const float* W3root = (const float*)d_in[12];
    float* out = (float*)d_out;

    const int N = in_sizes[0] / 2;
    const int E = in_sizes[2];
    const int* src = ei;
    const int* dst = ei + E;

    // -------- workspace layout (same total size as R17) --------
    ushort* h_hi = (ushort*)d_ws;
    ushort* h_lo = h_hi + (size_t)N * HIDDEN;
    ushort* a_hi = h_lo + (size_t)N * HIDDEN;
    ushort* a_lo = a_hi + (size_t)N * HIDDEN;
    int*   offs = (int*)(a_lo + (size_t)N * HIDDEN);
    int*   bsum = offs + N;
    size_t cpo  = (size_t)(bsum + SCAN_B - (int*)d_ws);
    cpo = (cpo + 1) & ~(size_t)1;          // 8B alignment
    int2*   cpack = (int2*)((int*)d_ws + cpo);
    size_t yvo  = (size_t)((char*)(cpack + E) - (char*)d_ws);
    yvo = (yvo + 15) & ~(size_t)15;        // 16B alignment
    float4* yv  = (float4*)((char*)d_ws + yvo);
    int* cnt  = (int*)cpack;               // alias: dead before k_fill writes cpack
    int* rank = (int*)d_ws;                // alias: dead before gatherfused writes h_hi
    float* z  = (float*)yv;                // alias: yv dead after gatherfused
    size_t wto = yvo + ((size_t)N * 3 * sizeof(float) + 15 & ~(size_t)15);
    wto = (wto + 15) & ~(size_t)15;
    ushort* wThi = (ushort*)((char*)d_ws + wto);          // 64KB
    ushort* wTlo = wThi + 128 * 256;                       // 64KB (within yv tail)

    const int nbScan = (N + SCAN_B - 1) / SCAN_B;

    // -------- CSR build --------
    hipMemsetAsync(cnt, 0, (size_t)N * sizeof(int), stream);
    k_hist <<<(E + 255) / 256, 256, 0, stream>>>(dst, cnt, rank, E);
    k_scan1<<<nbScan, SCAN_B, 0, stream>>>(cnt, offs, bsum, N);
    k_scan2<<<1, SCAN_B, 0, stream>>>(bsum, nbScan);
    k_scan3<<<nbScan, SCAN_B, 0, stream>>>(offs, bsum, N);
    k_fill <<<(E + 255) / 256, 256, 0, stream>>>(src, dst, ew, offs, rank, cpack, E);

    // -------- layer 1 aggregation (2ch) + y pack --------
    k_gather2<<<(N + 255) / 256, 256, 0, stream>>>(offs, cpack, x, yv, N, E);

    // -------- fused layer-2 aggregation + layer-1 node update (bf16 out) ----
    {
        long long threads = (long long)N * 64;
        k_gatherfused<<<(int)((threads + 255) / 256), 256, 0, stream>>>(
            offs, cpack, yv, W1rel, b1, W1root, h_hi, h_lo, a_hi, a_lo, N, E);
    }

    // -------- one-shot W2 split+transpose (yv dead now; writes its tail) ----
    k_splitw<<<128, 256, 0, stream>>>(W2rel, W2root, wThi, wTlo);

    // -------- MFMA layer-2 node update + layer-3 projection --------
    k_node2<<<(N + BM2 - 1) / BM2, 256, 0, stream>>>(
        a_hi, a_lo, h_hi, h_lo, wThi, wTlo, b2, W3rel, b3, W3root, z, out, N);

    // -------- layer 3 gather --------
    k_gather3<<<(N + 255) / 256, 256, 0, stream>>>(offs, cpack, z, out, N, E);
}

// Round 19
// 206.266 us; speedup vs baseline: 1.2436x; 1.2094x over previous
//
#include <hip/hip_runtime.h>

#define HIDDEN 128
#define NCHUNK 256
#define CBITS  9            // 512 nodes per coarse bucket (needs N < 2^17)

typedef float v2f __attribute__((ext_vector_type(2)));
typedef short short8 __attribute__((ext_vector_type(8)));
typedef float f32x4 __attribute__((ext_vector_type(4)));
__device__ __forceinline__ v2f v2s(float a) { v2f r; r.x = a; r.y = a; return r; }

// bf16 split helpers (RNE)
__device__ __forceinline__ ushort f2bf(float f) {
    uint u = __float_as_uint(f);
    u += 0x7FFFu + ((u >> 16) & 1u);
    return (ushort)(u >> 16);
}
__device__ __forceinline__ float bf2f(ushort h) {
    return __uint_as_float(((uint)h) << 16);
}

// ============== CSR build via two-level counting sort (NO global atomics) ===
// R19: k_hist's 1.6M device-scope atomics executed at the far coherence
// point (WRITE_SIZE 56MB = 1.6M x 32B RMW, ~24G atomics/s, VALU 0.5%) —
// a hardware floor for that structure. Counting sort moves all per-edge
// atomics into LDS (per-CU atomic units): coarse chunk histograms ->
// chunk/bucket prefix -> bucket scatter (LDS cursors) -> per-bucket fine
// CSR (LDS hist + scan + bucket-local scatter, 65KB span L2-combinable).

// Pass A: per-chunk coarse histogram (LDS atomics), store bh[c][b]
__global__ __launch_bounds__(256)
void k_bhist(const int* __restrict__ dst, int* __restrict__ bh, int E, int CS) {
    __shared__ int h[256];
    int c = blockIdx.x;
    h[threadIdx.x] = 0;
    __syncthreads();
    int beg = c * CS, end = min(E, beg + CS);
    for (int e = beg + threadIdx.x; e < end; e += 256)
        atomicAdd(&h[dst[e] >> CBITS], 1);
    __syncthreads();
    bh[c * 256 + threadIdx.x] = h[threadIdx.x];
}

// Pass B: chunk-prefix along c per bucket (raw, base added at use) + bucket
// bases via LDS scan. One block; loads 8-deep unrolled to stay pipelined.
__global__ __launch_bounds__(256)
void k_cscan(const int* __restrict__ bh, int* __restrict__ choff,
             int* __restrict__ bbase) {
    __shared__ int sm[256];
    int b = threadIdx.x;
    int acc = 0;
    for (int c = 0; c < NCHUNK; c += 8) {
        int v[8];
#pragma unroll
        for (int i = 0; i < 8; ++i) v[i] = bh[(c + i) * 256 + b];
#pragma unroll
        for (int i = 0; i < 8; ++i) { choff[(c + i) * 256 + b] = acc; acc += v[i]; }
    }
    int tot = acc;
    sm[b] = tot;
    __syncthreads();
    int run = tot;
    for (int d = 1; d < 256; d <<= 1) {
        int t = (b >= d) ? sm[b - d] : 0;
        __syncthreads();
        run += t;
        sm[b] = run;
        __syncthreads();
    }
    bbase[b] = run - tot;              // exclusive
    if (b == 255) bbase[256] = run;    // == E
}

// Pass C: scatter edges into coarse-bucket order. LDS cursors (atomic
// returns slot). staged word0 = src | (dst&511)<<17  (src < 2^17).
__global__ __launch_bounds__(256)
void k_scatter(const int* __restrict__ src, const int* __restrict__ dst,
               const float* __restrict__ ew, const int* __restrict__ choff,
               const int* __restrict__ bbase, int2* __restrict__ staged,
               int E, int CS) {
    __shared__ int cur[256];
    int c = blockIdx.x;
    cur[threadIdx.x] = bbase[threadIdx.x] + choff[c * 256 + threadIdx.x];
    __syncthreads();
    int beg = c * CS, end = min(E, beg + CS);
    for (int e = beg + threadIdx.x; e < end; e += 256) {
        int d = dst[e];
        int slot = atomicAdd(&cur[d >> CBITS], 1);
        int2 p;
        p.x = src[e] | ((d & 511) << 17);
        p.y = __float_as_int(ew[e]);
        staged[slot] = p;
    }
}

// Pass D: per-bucket fine CSR. LDS hist(512) -> LDS scan -> offs + cpack.
__global__ __launch_bounds__(256)
void k_fine(const int2* __restrict__ staged, const int* __restrict__ bbase,
            int* __restrict__ offs, int2* __restrict__ cpack, int N) {
    __shared__ int fc[512];
    __shared__ int fo[512];
    __shared__ int sm[256];
    int b = blockIdx.x;
    int t = threadIdx.x;
    int ebeg = bbase[b], eend = bbase[b + 1];
    fc[t] = 0; fc[t + 256] = 0;
    __syncthreads();
    for (int e = ebeg + t; e < eend; e += 256)
        atomicAdd(&fc[(staged[e].x >> 17) & 511], 1);
    __syncthreads();
    // exclusive scan of 512 (2 elems/thread)
    int a0 = fc[2 * t], a1 = fc[2 * t + 1];
    int s = a0 + a1;
    sm[t] = s;
    __syncthreads();
    int run = s;
    for (int d = 1; d < 256; d <<= 1) {
        int v = (t >= d) ? sm[t - d] : 0;
        __syncthreads();
        run += v;
        sm[t] = run;
        __syncthreads();
    }
    int ex = run - s;
    fo[2 * t] = ex;
    fo[2 * t + 1] = ex + a0;
    __syncthreads();
    int nb0 = b << CBITS;
#pragma unroll
    for (int q = 0; q < 2; ++q) {
        int i = q * 256 + t;
        int node = nb0 + i;
        if (node < N) offs[node] = ebeg + fo[i];
    }
    __syncthreads();                   // offs reads of fo done before cursor use
    for (int e = ebeg + t; e < eend; e += 256) {
        int2 p = staged[e];
        int dl = (p.x >> 17) & 511;
        int ls = atomicAdd(&fo[dl], 1);
        int2 q2;
        q2.x = p.x & 0x1FFFF;
        q2.y = p.y;
        cpack[ebeg + ls] = q2;
    }
}

__device__ __forceinline__ int end_of(const int* offs, int i, int N, int E) {
    return (i + 1 < N) ? offs[i + 1] : E;
}

// ================= layer 1: gather 2ch, emit combined y = (a0,a1,x0,x1) ====
__global__ __launch_bounds__(256)
void k_gather2(const int* __restrict__ offs, const int2* __restrict__ cpack,
               const float* __restrict__ x, float4* __restrict__ yv,
               int N, int E) {
    int i = blockIdx.x * 256 + threadIdx.x;
    if (i >= N) return;
    int start = offs[i], end = end_of(offs, i, N, E);
    float a0 = 0.f, a1 = 0.f;
    for (int j = start; j < end; ++j) {
        int2  p = cpack[j];
        int   s = p.x;
        float w = __int_as_float(p.y);
        float2 xv = *reinterpret_cast<const float2*>(x + (size_t)s * 2);
        a0 = fmaf(w, xv.x, a0);
        a1 = fmaf(w, xv.y, a1);
    }
    float2 xi = *reinterpret_cast<const float2*>(x + (size_t)i * 2);
    yv[i] = make_float4(a0, a1, xi.x, xi.y);
}

// ================= fused layer-2 aggregation + layer-1 node update ==========
// (R18 structure: coalesced window staging + readlane broadcast -> scalar
// yv loads; one SMEM round-trip per window.)
#define EDGE4(sK, wK)                                              \
    {                                                              \
        v2f t = B + v2s((sK).x) * WR0 + v2s((sK).y) * WR1          \
                  + v2s((sK).z) * WO0 + v2s((sK).w) * WO1;         \
        t = __builtin_elementwise_max(t, Z);                       \
        acc = acc + v2s(wK) * t;                                   \
    }

__global__ __launch_bounds__(256)
void k_gatherfused(const int* __restrict__ offs, const int2* __restrict__ cpack,
                   const float4* __restrict__ yv,
                   const float* __restrict__ W1rel, const float* __restrict__ b1,
                   const float* __restrict__ W1root,
                   ushort* __restrict__ h_hi, ushort* __restrict__ h_lo,
                   ushort* __restrict__ a_hi, ushort* __restrict__ a_lo,
                   int N, int E) {
    int wv   = (blockIdx.x * 256 + threadIdx.x) >> 6;
    int lane = threadIdx.x & 63;
    if (wv >= N) return;
    wv = __builtin_amdgcn_readfirstlane(wv);   // force scalar: loop control uniform

    const int c0 = lane * 2;
    const v2f WR0 = *reinterpret_cast<const v2f*>(W1rel  + c0);
    const v2f WR1 = *reinterpret_cast<const v2f*>(W1rel  + HIDDEN + c0);
    const v2f WO0 = *reinterpret_cast<const v2f*>(W1root + c0);
    const v2f WO1 = *reinterpret_cast<const v2f*>(W1root + HIDDEN + c0);
    const v2f B   = *reinterpret_cast<const v2f*>(b1 + c0);
    const v2f Z   = {0.f, 0.f};

    int start = offs[wv];
    int end   = (wv + 1 < N) ? offs[wv + 1] : E;
    v2f acc = {0.f, 0.f};

    for (int base = start; base < end; base += 64) {
        int nb = min(64, end - base);
        int sx = 0, wb = 0;
        if (lane < nb) {                       // ONE coalesced 8B/lane load
            int2 p = cpack[base + lane];
            sx = p.x; wb = p.y;
        }
        int k = 0;
        for (; k + 8 <= nb; k += 8) {
            int s0 = __builtin_amdgcn_readlane(sx, k + 0);
            int s1 = __builtin_amdgcn_readlane(sx, k + 1);
            int s2 = __builtin_amdgcn_readlane(sx, k + 2);
            int s3 = __builtin_amdgcn_readlane(sx, k + 3);
            int s4 = __builtin_amdgcn_readlane(sx, k + 4);
            int s5 = __builtin_amdgcn_readlane(sx, k + 5);
            int s6 = __builtin_amdgcn_readlane(sx, k + 6);
            int s7 = __builtin_amdgcn_readlane(sx, k + 7);
            float4 y0 = yv[s0]; float4 y1 = yv[s1];
            float4 y2 = yv[s2]; float4 y3 = yv[s3];
            float4 y4 = yv[s4]; float4 y5 = yv[s5];
            float4 y6 = yv[s6]; float4 y7 = yv[s7];
            float w0 = __int_as_float(__builtin_amdgcn_readlane(wb, k + 0));
            float w1 = __int_as_float(__builtin_amdgcn_readlane(wb, k + 1));
            float w2 = __int_as_float(__builtin_amdgcn_readlane(wb, k + 2));
            float w3 = __int_as_float(__builtin_amdgcn_readlane(wb, k + 3));
            float w4 = __int_as_float(__builtin_amdgcn_readlane(wb, k + 4));
            float w5 = __int_as_float(__builtin_amdgcn_readlane(wb, k + 5));
            float w6 = __int_as_float(__builtin_amdgcn_readlane(wb, k + 6));
            float w7 = __int_as_float(__builtin_amdgcn_readlane(wb, k + 7));
            EDGE4(y0, w0) EDGE4(y1, w1) EDGE4(y2, w2) EDGE4(y3, w3)
            EDGE4(y4, w4) EDGE4(y5, w5) EDGE4(y6, w6) EDGE4(y7, w7)
        }
        for (; k + 4 <= nb; k += 4) {
            int s0 = __builtin_amdgcn_readlane(sx, k + 0);
            int s1 = __builtin_amdgcn_readlane(sx, k + 1);
            int s2 = __builtin_amdgcn_readlane(sx, k + 2);
            int s3 = __builtin_amdgcn_readlane(sx, k + 3);
            float4 y0 = yv[s0]; float4 y1 = yv[s1];
            float4 y2 = yv[s2]; float4 y3 = yv[s3];
            float w0 = __int_as_float(__builtin_amdgcn_readlane(wb, k + 0));
            float w1 = __int_as_float(__builtin_amdgcn_readlane(wb, k + 1));
            float w2 = __int_as_float(__builtin_amdgcn_readlane(wb, k + 2));
            float w3 = __int_as_float(__builtin_amdgcn_readlane(wb, k + 3));
            EDGE4(y0, w0) EDGE4(y1, w1) EDGE4(y2, w2) EDGE4(y3, w3)
        }
        for (; k < nb; ++k) {                  // scalar tail (<=3)
            int s0 = __builtin_amdgcn_readlane(sx, k);
            float4 y0 = yv[s0];
            float w0 = __int_as_float(__builtin_amdgcn_readlane(wb, k));
            EDGE4(y0, w0)
        }
    }

    // aggr -> bf16 hi/lo
    {
        ushort hx = f2bf(acc.x);
        ushort lx = f2bf(acc.x - bf2f(hx));
        ushort hy = f2bf(acc.y);
        ushort ly = f2bf(acc.y - bf2f(hy));
        ushort2 hv2; hv2.x = hx; hv2.y = hy;
        ushort2 lv2; lv2.x = lx; lv2.y = ly;
        *reinterpret_cast<ushort2*>(a_hi + (size_t)wv * HIDDEN + c0) = hv2;
        *reinterpret_cast<ushort2*>(a_lo + (size_t)wv * HIDDEN + c0) = lv2;
    }

    // fused k_node1: this wave's own h1 row -> bf16 hi/lo
    {
        float4 y = yv[wv];
        v2f t = B + v2s(y.x) * WR0 + v2s(y.y) * WR1
                  + v2s(y.z) * WO0 + v2s(y.w) * WO1;
        t = __builtin_elementwise_max(t, Z);
        ushort hx = f2bf(t.x);
        ushort lx = f2bf(t.x - bf2f(hx));
        ushort hy = f2bf(t.y);
        ushort ly = f2bf(t.y - bf2f(hy));
        ushort2 hv2; hv2.x = hx; hv2.y = hy;
        ushort2 lv2; lv2.x = lx; lv2.y = ly;
        *reinterpret_cast<ushort2*>(h_hi + (size_t)wv * HIDDEN + c0) = hv2;
        *reinterpret_cast<ushort2*>(h_lo + (size_t)wv * HIDDEN + c0) = lv2;
    }
}

// ================= one-shot W2 split + transpose ============================
__global__ __launch_bounds__(256)
void k_splitw(const float* __restrict__ Wrel, const float* __restrict__ Wroot,
              ushort* __restrict__ wThi, ushort* __restrict__ wTlo) {
    int idx = blockIdx.x * 256 + threadIdx.x;   // 0..32767
    int k = idx >> 7;          // 0..255
    int n = idx & 127;
    float v = (k < 128) ? Wrel[(size_t)k * HIDDEN + n]
                        : Wroot[(size_t)(k - 128) * HIDDEN + n];
    ushort hb = f2bf(v);
    ushort lb = f2bf(v - bf2f(hb));
    wThi[(size_t)n * 256 + k] = hb;
    wTlo[(size_t)n * 256 + k] = lb;
}

// ============ layer-2 node update on the MATRIX pipe + layer-3 fusion =======
#define BM2 64
#define W3_STRIDE 7
#define XS_LD 40   // ushorts per LDS row: 32 k + 8 pad (80B, 16B-aligned)

__global__ __launch_bounds__(256)
void k_node2(const ushort* __restrict__ a_hi, const ushort* __restrict__ a_lo,
             const ushort* __restrict__ h_hi, const ushort* __restrict__ h_lo,
             const ushort* __restrict__ wThi, const ushort* __restrict__ wTlo,
             const float* __restrict__ b,
             const float* __restrict__ W3rel, const float* __restrict__ b3,
             const float* __restrict__ W3root,
             float* __restrict__ z, float* __restrict__ out, int N) {
    __shared__ __align__(16) ushort Xhi[BM2 * XS_LD];
    __shared__ __align__(16) ushort Xlo[BM2 * XS_LD];
    __shared__ __align__(16) ushort Whi[HIDDEN * XS_LD];
    __shared__ __align__(16) ushort Wlo[HIDDEN * XS_LD];
    __shared__ float W3s[HIDDEN * W3_STRIDE];

    const int tid  = threadIdx.x;
    const int lane = tid & 63;
    const int wid  = tid >> 6;
    const int ci   = lane & 15;
    const int kb   = lane >> 4;          // k-block 0..3
    const int nb   = blockIdx.x * BM2;

    if (tid < HIDDEN) {
#pragma unroll
        for (int c = 0; c < 3; ++c) {
            W3s[tid * W3_STRIDE + c]     = W3rel [tid * 3 + c];
            W3s[tid * W3_STRIDE + 3 + c] = W3root[tid * 3 + c];
        }
    }

    f32x4 acc[8];
#pragma unroll
    for (int tile = 0; tile < 8; ++tile) {
        float bb = b[tile * 16 + ci];
        f32x4 v; v[0] = bb; v[1] = bb; v[2] = bb; v[3] = bb;
        acc[tile] = v;
    }

    // staging index precompute
    const int sr  = tid >> 2;            // X row 0..63
    const int skq = (tid & 3) * 8;       // X k offset {0,8,16,24}

    // K = 256: 8 phases of 32. t<4: aggr; t>=4: h. W index linear in t.
    for (int t = 0; t < 8; ++t) {
        const ushort* Ahi = (t < 4) ? a_hi : h_hi;
        const ushort* Alo = (t < 4) ? a_lo : h_lo;
        const int kc = (t & 3) * 32;

        __syncthreads();                 // previous compute done before overwrite
        // stage X tile (pre-split bf16): 1 b128 per array per thread
        {
            int gr = nb + sr; if (gr >= N) gr = N - 1;
            size_t gofs = (size_t)gr * HIDDEN + kc + skq;
            *reinterpret_cast<short8*>(&Xhi[sr * XS_LD + skq]) =
                *reinterpret_cast<const short8*>(Ahi + gofs);
            *reinterpret_cast<short8*>(&Xlo[sr * XS_LD + skq]) =
                *reinterpret_cast<const short8*>(Alo + gofs);
        }
        // stage W tile: pure b128 copy from pre-split pre-transposed wT
#pragma unroll
        for (int q = 0; q < 2; ++q) {
            int idx = q * 256 + tid;     // 0..511
            int n  = idx >> 2;           // 0..127
            int kq = (idx & 3) * 8;      // 0,8,16,24
            size_t g = (size_t)n * 256 + t * 32 + kq;
            *reinterpret_cast<short8*>(&Whi[n * XS_LD + kq]) =
                *reinterpret_cast<const short8*>(wThi + g);
            *reinterpret_cast<short8*>(&Wlo[n * XS_LD + kq]) =
                *reinterpret_cast<const short8*>(wTlo + g);
        }
        __syncthreads();

        // A frags for this wave's 16-row tile (shared across all col tiles)
        int rl = wid * 16 + ci;
        short8 afh = *reinterpret_cast<const short8*>(&Xhi[rl * XS_LD + kb * 8]);
        short8 afl = *reinterpret_cast<const short8*>(&Xlo[rl * XS_LD + kb * 8]);
#pragma unroll
        for (int tile = 0; tile < 8; ++tile) {
            int nl = tile * 16 + ci;
            short8 bfh = *reinterpret_cast<const short8*>(&Whi[nl * XS_LD + kb * 8]);
            short8 bfl = *reinterpret_cast<const short8*>(&Wlo[nl * XS_LD + kb * 8]);
            acc[tile] = __builtin_amdgcn_mfma_f32_16x16x32_bf16(afh, bfh, acc[tile], 0, 0, 0);
            acc[tile] = __builtin_amdgcn_mfma_f32_16x16x32_bf16(afh, bfl, acc[tile], 0, 0, 0);
            acc[tile] = __builtin_amdgcn_mfma_f32_16x16x32_bf16(afl, bfh, acc[tile], 0, 0, 0);
        }
    }

    // epilogue: relu -> per-thread rank-8 partials vs LDS W3 -> width-16 shfl
    const float b30 = b3[0], b31 = b3[1], b32 = b3[2];
#pragma unroll
    for (int m = 0; m < 4; ++m) {
        int node = nb + wid * 16 + kb * 4 + m;
        float zr0 = 0.f, zr1 = 0.f, zr2 = 0.f;
        float zo0 = 0.f, zo1 = 0.f, zo2 = 0.f;
#pragma unroll
        for (int tile = 0; tile < 8; ++tile) {
            float hv = fmaxf(acc[tile][m], 0.f);
            const float* w3 = &W3s[(tile * 16 + ci) * W3_STRIDE];
            zr0 = fmaf(hv, w3[0], zr0); zr1 = fmaf(hv, w3[1], zr1); zr2 = fmaf(hv, w3[2], zr2);
            zo0 = fmaf(hv, w3[3], zo0); zo1 = fmaf(hv, w3[4], zo1); zo2 = fmaf(hv, w3[5], zo2);
        }
#pragma unroll
        for (int d = 8; d >= 1; d >>= 1) {
            zr0 += __shfl_down(zr0, d, 16);
            zr1 += __shfl_down(zr1, d, 16);
            zr2 += __shfl_down(zr2, d, 16);
            zo0 += __shfl_down(zo0, d, 16);
            zo1 += __shfl_down(zo1, d, 16);
            zo2 += __shfl_down(zo2, d, 16);
        }
        if (ci == 0 && node < N) {
            z[(size_t)node * 3 + 0] = zr0;
            z[(size_t)node * 3 + 1] = zr1;
            z[(size_t)node * 3 + 2] = zr2;
            out[(size_t)node * 3 + 0] = zo0 + b30;
            out[(size_t)node * 3 + 1] = zo1 + b31;
            out[(size_t)node * 3 + 2] = zo2 + b32;
        }
    }
}

// ================= layer 3 gather =====================
__global__ __launch_bounds__(256)
void k_gather3(const int* __restrict__ offs, const int2* __restrict__ cpack,
               const float* __restrict__ z, float* __restrict__ out,
               int N, int E) {
    int i = blockIdx.x * 256 + threadIdx.x;
    if (i >= N) return;
    int start = offs[i], end = end_of(offs, i, N, E);
    float a0 = 0.f, a1 = 0.f, a2 = 0.f;
    for (int j = start; j < end; ++j) {
        int2  p = cpack[j];
        int   s = p.x;
        float w = __int_as_float(p.y);
        const float* zp = z + (size_t)s * 3;
        a0 = fmaf(w, zp[0], a0);
        a1 = fmaf(w, zp[1], a1);
        a2 = fmaf(w, zp[2], a2);
    }
    out[(size_t)i * 3 + 0] += a0;
    out[(size_t)i * 3 + 1] += a1;
    out[(size_t)i * 3 + 2] += a2;
}

extern "C" void kernel_launch(void* const* d_in, const int* in_sizes, int n_in,
                              void* d_out, int out_size, void* d_ws, size_t ws_size,
                              hipStream_t stream) {
    const float* x      = (const float*)d_in[0];
    const int*   ei     = (const int*)  d_in[1];
    const float* ew     = (const float*)d_in[2];
    const float* W1rel  = (const float*)d_in[4];
    const float* b1     = (const float*)d_in[5];
    const float* W1root = (const float*)d_in[6];
    const float* W2rel  = (const float*)d_in[7];
    const float* b2     = (const float*)d_in[8];
    const float* W2root = (const float*)d_in[9];
    const float* W3rel  = (const float*)d_in[10];
    const float* b3     = (const float*)d_in[11];
    const float* W3root = (const float*)d_in[12];
    float* out = (float*)d_out;

    const int N = in_sizes[0] / 2;
    const int E = in_sizes[2];
    const int* src = ei;
    const int* dst = ei + E;

    // -------- workspace layout (same total size as R18) --------
    // h region  : h_hi + h_lo bf16 (front 12.8MB aliases staged during CSR build)
    // aggr reg. : a_hi + a_lo bf16 (front 513KB aliases bh/choff/bbase in build)
    // offs : N int
    // cpack : E int2
    // yv : N float4 (dead after gatherfused): front N*3 f32 = z; tail wThi/wTlo
    ushort* h_hi = (ushort*)d_ws;
    ushort* h_lo = h_hi + (size_t)N * HIDDEN;
    ushort* a_hi = h_lo + (size_t)N * HIDDEN;
    ushort* a_lo = a_hi + (size_t)N * HIDDEN;
    int*   offs = (int*)(a_lo + (size_t)N * HIDDEN);
    size_t cpo  = (size_t)(offs + N - (int*)d_ws);
    cpo = (cpo + 1) & ~(size_t)1;          // 8B alignment
    int2*   cpack = (int2*)((int*)d_ws + cpo);
    size_t yvo  = (size_t)((char*)(cpack + E) - (char*)d_ws);
    yvo = (yvo + 15) & ~(size_t)15;        // 16B alignment
    float4* yv  = (float4*)((char*)d_ws + yvo);
    float* z  = (float*)yv;                // alias: yv dead after gatherfused
    size_t wto = yvo + ((size_t)N * 3 * sizeof(float) + 15 & ~(size_t)15);
    wto = (wto + 15) & ~(size_t)15;
    ushort* wThi = (ushort*)((char*)d_ws + wto);          // 64KB
    ushort* wTlo = wThi + 128 * 256;                       // 64KB (within yv tail)

    // CSR-build scratch (all dead before gatherfused writes h/a regions):
    int2* staged = (int2*)d_ws;            // E int2 = 12.8MB, aliases h front
    int*  bh     = (int*)a_hi;             // 256*256 ints = 256KB
    int*  choff  = bh + 256 * 256;         // 256KB
    int*  bbase  = choff + 256 * 256;      // 257 ints

    const int CS = (E + NCHUNK - 1) / NCHUNK;
    const int NB = (N + 511) >> CBITS;     // coarse buckets (needs N < 2^17)

    // -------- CSR build: two-level counting sort, zero global atomics ------
    k_bhist  <<<NCHUNK, 256, 0, stream>>>(dst, bh, E, CS);
    k_cscan  <<<1, 256, 0, stream>>>(bh, choff, bbase);
    k_scatter<<<NCHUNK, 256, 0, stream>>>(src, dst, ew, choff, bbase, staged, E, CS);
    k_fine   <<<NB, 256, 0, stream>>>(staged, bbase, offs, cpack, N);

    // -------- layer 1 aggregation (2ch) + y pack --------
    k_gather2<<<(N + 255) / 256, 256, 0, stream>>>(offs, cpack, x, yv, N, E);

    // -------- fused layer-2 aggregation + layer-1 node update (bf16 out) ----
    {
        long long threads = (long long)N * 64;
        k_gatherfused<<<(int)((threads + 255) / 256), 256, 0, stream>>>(
            offs, cpack, yv, W1rel, b1, W1root, h_hi, h_lo, a_hi, a_lo, N, E);
    }

    // -------- one-shot W2 split+transpose (yv dead now; writes its tail) ----
    k_splitw<<<128, 256, 0, stream>>>(W2rel, W2root, wThi, wTlo);

    // -------- MFMA layer-2 node update + layer-3 projection --------
    k_node2<<<(N + BM2 - 1) / BM2, 256, 0, stream>>>(
        a_hi, a_lo, h_hi, h_lo, wThi, wTlo, b2, W3rel, b3, W3root, z, out, N);

    // -------- layer 3 gather --------
    k_gather3<<<(N + 255) / 256, 256, 0, stream>>>(offs, cpack, z, out, N, E);
}